// Round 3
// baseline (45.212 us; speedup 1.0000x reference)
//
#include <hip/hip_runtime.h>

// Problem constants (from reference)
constexpr int N = 2;
constexpr int C = 20;
constexpr int H = 64;
constexpr int W = 2048;          // power of two -> wrap via & (W-1)
constexpr int HW = H * W;

constexpr int OPT  = 4;          // outputs per thread (float4 column)
constexpr int BLK  = 256;
constexpr int TILE = OPT * BLK;  // 1024 outputs per block along w

__global__ __launch_bounds__(BLK, 1)
void lcl_xyz_kernel(const float* __restrict__ xyz,
                    const float* __restrict__ softmax,
                    const int* __restrict__ mask,
                    float* __restrict__ out) {
    const int t  = threadIdx.x;
    const int bw = blockIdx.x & 1;           // W/TILE = 2 tiles per row
    const int h  = (blockIdx.x >> 1) & 63;
    const int n  = blockIdx.x >> 7;
    const int w0 = bw * TILE + OPT * t;      // first output col (4-aligned)

    // The 3 aligned float4 column groups covering cols w0-4 .. w0+7
    const int c0 = (w0 - 4) & (W - 1);
    const int c1 = w0;
    const int c2 = (w0 + 4) & (W - 1);

    // Clipped rows + validity
    int  hc[5];
    bool hv[5];
    #pragma unroll
    for (int r = 0; r < 5; ++r) {
        int hh = h - 2 + r;
        hv[r] = (unsigned)hh < (unsigned)H;
        hc[r] = min(max(hh, 0), H - 1);
    }

    const float* xb = xyz + (size_t)(n * 3 + 0) * HW;
    const float* yb = xyz + (size_t)(n * 3 + 1) * HW;
    const float* zb = xyz + (size_t)(n * 3 + 2) * HW;
    const int*   mb = mask + (size_t)n * HW;

    // Centers: x,y,z at row h, cols w0..w0+3
    const float4 cx4 = *(const float4*)(xb + h * W + c1);
    const float4 cy4 = *(const float4*)(yb + h * W + c1);
    const float4 cz4 = *(const float4*)(zb + h * W + c1);
    const float cx[4] = {cx4.x, cx4.y, cx4.z, cx4.w};
    const float cy[4] = {cy4.x, cy4.y, cy4.z, cy4.w};
    const float cz[4] = {cz4.x, cz4.y, cz4.z, cz4.w};

    // ---- Weight phase: 100 gaussian*mask*valid weights in registers ----
    // wgt[r][q][j]: tap col index i = q+j+2 into the 12-float row span
    float wgt[5][4][5];
    #pragma unroll
    for (int r = 0; r < 5; ++r) {
        const int ro = hc[r] * W;
        float xv[12], yv[12], zv[12];
        int   mv[12];
        {
            float4 a0 = *(const float4*)(xb + ro + c0);
            float4 a1 = *(const float4*)(xb + ro + c1);
            float4 a2 = *(const float4*)(xb + ro + c2);
            xv[0]=a0.x; xv[1]=a0.y; xv[2]=a0.z; xv[3]=a0.w;
            xv[4]=a1.x; xv[5]=a1.y; xv[6]=a1.z; xv[7]=a1.w;
            xv[8]=a2.x; xv[9]=a2.y; xv[10]=a2.z; xv[11]=a2.w;
        }
        {
            float4 a0 = *(const float4*)(yb + ro + c0);
            float4 a1 = *(const float4*)(yb + ro + c1);
            float4 a2 = *(const float4*)(yb + ro + c2);
            yv[0]=a0.x; yv[1]=a0.y; yv[2]=a0.z; yv[3]=a0.w;
            yv[4]=a1.x; yv[5]=a1.y; yv[6]=a1.z; yv[7]=a1.w;
            yv[8]=a2.x; yv[9]=a2.y; yv[10]=a2.z; yv[11]=a2.w;
        }
        {
            float4 a0 = *(const float4*)(zb + ro + c0);
            float4 a1 = *(const float4*)(zb + ro + c1);
            float4 a2 = *(const float4*)(zb + ro + c2);
            zv[0]=a0.x; zv[1]=a0.y; zv[2]=a0.z; zv[3]=a0.w;
            zv[4]=a1.x; zv[5]=a1.y; zv[6]=a1.z; zv[7]=a1.w;
            zv[8]=a2.x; zv[9]=a2.y; zv[10]=a2.z; zv[11]=a2.w;
        }
        {
            int4 a0 = *(const int4*)(mb + ro + c0);
            int4 a1 = *(const int4*)(mb + ro + c1);
            int4 a2 = *(const int4*)(mb + ro + c2);
            mv[0]=a0.x; mv[1]=a0.y; mv[2]=a0.z; mv[3]=a0.w;
            mv[4]=a1.x; mv[5]=a1.y; mv[6]=a1.z; mv[7]=a1.w;
            mv[8]=a2.x; mv[9]=a2.y; mv[10]=a2.z; mv[11]=a2.w;
        }
        #pragma unroll
        for (int q = 0; q < 4; ++q) {
            #pragma unroll
            for (int j = 0; j < 5; ++j) {
                const int i = q + j + 2;
                float dx = xv[i] - cx[q];
                float dy = yv[i] - cy[q];
                float dz = zv[i] - cz[q];
                float d2 = dx * dx + dy * dy + dz * dz;
                float g  = __expf(-0.5f * d2);       // GAUSS_DEN = 2*sigma^2 = 2
                wgt[r][q][j] = (hv[r] && mv[i]) ? g : 0.0f;
            }
        }
    }

    // ---- Class loop: 15 coalesced b128 loads + 100 FMA per class ----
    const float* smb = softmax + (size_t)n * C * HW;
    float*       ob  = out     + (size_t)n * C * HW + (size_t)h * W + c1;

    for (int c = 0; c < C; ++c) {
        const float* sc = smb + (size_t)c * HW;
        float acc[4] = {0.f, 0.f, 0.f, 0.f};
        #pragma unroll
        for (int r = 0; r < 5; ++r) {
            const float* p = sc + hc[r] * W;
            float4 a0 = *(const float4*)(p + c0);
            float4 a1 = *(const float4*)(p + c1);
            float4 a2 = *(const float4*)(p + c2);
            float v[12];
            v[0]=a0.x; v[1]=a0.y; v[2]=a0.z; v[3]=a0.w;
            v[4]=a1.x; v[5]=a1.y; v[6]=a1.z; v[7]=a1.w;
            v[8]=a2.x; v[9]=a2.y; v[10]=a2.z; v[11]=a2.w;
            #pragma unroll
            for (int q = 0; q < 4; ++q) {
                #pragma unroll
                for (int j = 0; j < 5; ++j) {
                    acc[q] = fmaf(wgt[r][q][j], v[q + j + 2], acc[q]);
                }
            }
        }
        float4 o = {acc[0], acc[1], acc[2], acc[3]};
        *(float4*)(ob + (size_t)c * HW) = o;
    }
}

extern "C" void kernel_launch(void* const* d_in, const int* in_sizes, int n_in,
                              void* d_out, int out_size, void* d_ws, size_t ws_size,
                              hipStream_t stream) {
    const float* xyz     = (const float*)d_in[0];
    const float* softmax = (const float*)d_in[1];
    const int*   mask    = (const int*)d_in[2];
    float*       out     = (float*)d_out;

    const int grid = N * H * (W / TILE);     // 2*64*2 = 256 blocks
    lcl_xyz_kernel<<<grid, BLK, 0, stream>>>(xyz, softmax, mask, out);
}

// Round 4
// 27.539 us; speedup vs baseline: 1.6417x; 1.6417x over previous
//
#include <hip/hip_runtime.h>

// Problem constants (from reference)
constexpr int N = 2;
constexpr int C = 20;
constexpr int H = 64;
constexpr int W = 2048;          // power of two -> wrap via & (W-1)
constexpr int HW = H * W;

constexpr int BLK   = 256;
constexpr int OPT   = 2;              // outputs per thread
constexpr int TILE  = BLK * OPT;      // 512 outputs per block along w
constexpr int LCOLS = TILE + 8;       // 520 staged cols: w0-4 .. w0+515
constexpr int F4    = LCOLS / 4;      // 130 float4 groups per row
constexpr int ITEMS = 5 * F4;         // 650 float4 items per channel slab

// 16B async global->LDS. Item->LDS mapping is linear (row r*2080B + k*16B == it*16B),
// so the wave-uniform-base + lane*16 destination rule holds.
#define GLDS16(g, l)                                                        \
    __builtin_amdgcn_global_load_lds(                                       \
        (const __attribute__((address_space(1))) void*)(g),                 \
        (__attribute__((address_space(3))) void*)(l), 16, 0, 0)

__global__ __launch_bounds__(BLK)
void lcl_xyz_kernel(const float* __restrict__ xyz,
                    const float* __restrict__ softmax,
                    const int* __restrict__ mask,
                    float* __restrict__ out) {
    __shared__ float sx[5][LCOLS];
    __shared__ float sy[5][LCOLS];
    __shared__ float sz[5][LCOLS];
    __shared__ int   sk[5][LCOLS];
    __shared__ float sp[2][5][LCOLS];   // double-buffered softmax slab

    const int t  = threadIdx.x;
    const int bw = blockIdx.x & 3;           // W/TILE = 4 tiles per row
    const int h  = (blockIdx.x >> 2) & 63;
    const int n  = blockIdx.x >> 8;
    const int w0 = bw * TILE;

    int hc[5];
    #pragma unroll
    for (int r = 0; r < 5; ++r) hc[r] = min(max(h - 2 + r, 0), H - 1);

    const float* xb  = xyz + (size_t)(n * 3 + 0) * HW;
    const float* yb  = xyz + (size_t)(n * 3 + 1) * HW;
    const float* zb  = xyz + (size_t)(n * 3 + 2) * HW;
    const int*   mb  = mask + (size_t)n * HW;
    const float* smb = softmax + (size_t)n * C * HW;

    // ---- Stage xyz + mask slabs (async, 16B, linear LDS dest) ----
    #pragma unroll
    for (int s = 0; s < 3; ++s) {
        int it = t + BLK * s;
        if (it < ITEMS) {
            int r   = it / F4;
            int k   = it - r * F4;
            int off = hc[r] * W + ((w0 - 4 + 4 * k) & (W - 1));
            GLDS16(xb + off, (char*)&sx[0][0] + it * 16);
            GLDS16(yb + off, (char*)&sy[0][0] + it * 16);
            GLDS16(zb + off, (char*)&sz[0][0] + it * 16);
            GLDS16(mb + off, (char*)&sk[0][0] + it * 16);
        }
    }
    // ---- Stage class 0 softmax slab ----
    #pragma unroll
    for (int s = 0; s < 3; ++s) {
        int it = t + BLK * s;
        if (it < ITEMS) {
            int r   = it / F4;
            int k   = it - r * F4;
            int off = hc[r] * W + ((w0 - 4 + 4 * k) & (W - 1));
            GLDS16(smb + off, (char*)&sp[0][0][0] + it * 16);
        }
    }
    __syncthreads();

    // ---- Weight phase: 50 gaussian*mask*valid weights in registers ----
    const int base = 2 * t + 2;              // staged col of leftmost tap
    const float cx0 = sx[2][base + 2], cx1 = sx[2][base + 3];
    const float cy0 = sy[2][base + 2], cy1 = sy[2][base + 3];
    const float cz0 = sz[2][base + 2], cz1 = sz[2][base + 3];

    float wa[5][5], wb[5][5];
    #pragma unroll
    for (int r = 0; r < 5; ++r) {
        const bool hv = (unsigned)(h - 2 + r) < (unsigned)H;
        float xv[6], yv[6], zv[6];
        int   mv[6];
        *(float2*)&xv[0] = *(const float2*)&sx[r][base];
        *(float2*)&xv[2] = *(const float2*)&sx[r][base + 2];
        *(float2*)&xv[4] = *(const float2*)&sx[r][base + 4];
        *(float2*)&yv[0] = *(const float2*)&sy[r][base];
        *(float2*)&yv[2] = *(const float2*)&sy[r][base + 2];
        *(float2*)&yv[4] = *(const float2*)&sy[r][base + 4];
        *(float2*)&zv[0] = *(const float2*)&sz[r][base];
        *(float2*)&zv[2] = *(const float2*)&sz[r][base + 2];
        *(float2*)&zv[4] = *(const float2*)&sz[r][base + 4];
        *(int2*)&mv[0]   = *(const int2*)&sk[r][base];
        *(int2*)&mv[2]   = *(const int2*)&sk[r][base + 2];
        *(int2*)&mv[4]   = *(const int2*)&sk[r][base + 4];
        #pragma unroll
        for (int j = 0; j < 5; ++j) {
            {
                float dx = xv[j] - cx0, dy = yv[j] - cy0, dz = zv[j] - cz0;
                float g  = __expf(-0.5f * (dx * dx + dy * dy + dz * dz));
                wa[r][j] = (hv && mv[j]) ? g : 0.0f;
            }
            {
                float dx = xv[j + 1] - cx1, dy = yv[j + 1] - cy1, dz = zv[j + 1] - cz1;
                float g  = __expf(-0.5f * (dx * dx + dy * dy + dz * dz));
                wb[r][j] = (hv && mv[j + 1]) ? g : 0.0f;
            }
        }
    }

    // ---- Class loop: prefetch next slab (async), compute current, 1 barrier ----
    float* ob = out + (size_t)n * C * HW + (size_t)h * W + w0 + 2 * t;

    for (int c = 0; c < C; ++c) {
        if (c + 1 < C) {
            const float* sc = smb + (size_t)(c + 1) * HW;
            char*        lb = (char*)&sp[(c + 1) & 1][0][0];
            #pragma unroll
            for (int s = 0; s < 3; ++s) {
                int it = t + BLK * s;
                if (it < ITEMS) {
                    int r   = it / F4;
                    int k   = it - r * F4;
                    int off = hc[r] * W + ((w0 - 4 + 4 * k) & (W - 1));
                    GLDS16(sc + off, lb + it * 16);
                }
            }
        }

        const float (*spc)[LCOLS] = sp[c & 1];
        float a0 = 0.0f, a1 = 0.0f;
        #pragma unroll
        for (int r = 0; r < 5; ++r) {
            float v[6];
            *(float2*)&v[0] = *(const float2*)&spc[r][base];
            *(float2*)&v[2] = *(const float2*)&spc[r][base + 2];
            *(float2*)&v[4] = *(const float2*)&spc[r][base + 4];
            #pragma unroll
            for (int j = 0; j < 5; ++j) {
                a0 = fmaf(wa[r][j], v[j],     a0);
                a1 = fmaf(wb[r][j], v[j + 1], a1);
            }
        }
        float2 o; o.x = a0; o.y = a1;
        *(float2*)(ob + (size_t)c * HW) = o;

        __syncthreads();   // drains prefetch; next iter's buffer is ready
    }
}

extern "C" void kernel_launch(void* const* d_in, const int* in_sizes, int n_in,
                              void* d_out, int out_size, void* d_ws, size_t ws_size,
                              hipStream_t stream) {
    const float* xyz     = (const float*)d_in[0];
    const float* softmax = (const float*)d_in[1];
    const int*   mask    = (const int*)d_in[2];
    float*       out     = (float*)d_out;

    const int grid = N * H * (W / TILE);     // 2*64*4 = 512 blocks
    lcl_xyz_kernel<<<grid, BLK, 0, stream>>>(xyz, softmax, mask, out);
}